// Round 6
// baseline (68876.520 us; speedup 1.0000x reference)
//
#include <hip/hip_runtime.h>
#include <hip/hip_bf16.h>

#define NN 512
#define DEG 8
#define FD 128
#define HD 256
#define MD 256
#define OD 64
#define PD 2
#define HIST 10
#define TOTAL (10 * NN)       /* 5120 queue entries processed */
#define NPAR 648
#define INV_SQRT_H 0.0625f

typedef __hip_bfloat16 bf16;

// bit-level finite guard (fast-math-proof)
__device__ __forceinline__ float finz(float x) {
  unsigned u = __float_as_uint(x);
  return (((u >> 23) & 0xFFu) == 0xFFu) ? 0.f : x;
}

// dtype-polymorphic load: BF=true -> bf16 array, BF=false -> float array
template <bool BF>
__device__ __forceinline__ float ldin(const void* p, int idx) {
  if (BF) return __bfloat162float(((const bf16*)p)[idx]);
  return ((const float*)p)[idx];
}

// ---- static device scratch ----
__device__ float g_hist[NN * HIST * HD];    // ring buffers, 5.24 MB
__device__ float g_msgb[NPAR * MD];         // messages of entries with children
__device__ float g_WrS[HD * HD];            // sum of 4 Wr row-blocks
__device__ float g_WkT[HD * HD];            // Wk transposed (fp32: no extra quantization)
__device__ int   g_counts[NN];
__device__ int   g_dtype;                   // 1 = float tensors are bf16, 0 = float32
__device__ int   g_i64;                     // 1 = neighbors int64

__device__ __forceinline__ int decode_S(const int* dS) {
  int r = dS[0];                            // little-endian: works for i32 and i64
  if (r >= 1 && r <= NN) return r;
  float f = __int_as_float(r);
  if (f >= 1.f && f <= (float)NN) return (int)f;
  unsigned u = ((unsigned)r & 0xFFFFu) << 16;
  float g = __uint_as_float(u);
  if (g >= 1.f && g <= (float)NN) return (int)g;
  return 64;
}

__device__ __forceinline__ int get_nbr(const int* nbrs, int i64, int n, int d) {
  int v = i64 ? nbrs[2 * (n * DEG + d)] : nbrs[n * DEG + d];
  return (v < 0) ? 0 : (v >= NN ? NN - 1 : v);
}

// ---------------- dtype detection from data statistics ----------------
// f32 words: low 16 bits = mantissa (uniform) -> rarely a plausible small bf16.
// bf16 words: low 16 bits = an even-index normal(0,1) bf16 -> almost always plausible.
__global__ void k_detect(const unsigned* __restrict__ xa_words,
                         const int* __restrict__ nbrs_words) {
  if (threadIdx.x != 0 || blockIdx.x != 0) return;
  int cnt = 0;
  for (int w = 0; w < 64; ++w) {
    unsigned lo = xa_words[w] & 0xFFFFu;
    float vb = __uint_as_float(lo << 16);   // interpret low16 as bf16
    float av = fabsf(vb);
    if (av > 0.000244140625f && av < 64.f) ++cnt;   // (2^-12, 2^6)
  }
  g_dtype = (cnt >= 32) ? 1 : 0;
  int allz = 1;                              // int64 nbrs: odd words are high halves = 0
  for (int w = 1; w < 16; w += 2) allz &= (nbrs_words[w] == 0);
  g_i64 = allz;
}

// ---------------- prep: transpose Wk, fold Wr ----------------
template <bool BF>
__global__ void k_prep(const void* __restrict__ Wk, const void* __restrict__ Wr) {
  if ((g_dtype != 0) != BF) return;
  const int b = blockIdx.x, t = threadIdx.x;
  g_WkT[b * HD + t] = ldin<BF>(Wk, t * HD + b);   // WkT[b][t] = Wk[t][b]
  float s = 0.f;
#pragma unroll
  for (int q = 0; q < 4; ++q) s += ldin<BF>(Wr, (q * HD + b) * HD + t);
  g_WrS[b * HD + t] = s;
}

// ---------------- encoded = xa @ We + be -> hist slot 0 ----------------
template <bool BF>
__global__ void k_encode(const void* __restrict__ xa, const void* __restrict__ We,
                         const void* __restrict__ be) {
  if ((g_dtype != 0) != BF) return;
  __shared__ float sxa[FD];
  int n = blockIdx.x, t = threadIdx.x;
  if (t < FD) sxa[t] = ldin<BF>(xa, n * FD + t);
  __syncthreads();
  float acc = ldin<BF>(be, t);
  for (int f = 0; f < FD; ++f) acc += sxa[f] * ldin<BF>(We, f * HD + t);
  g_hist[(size_t)(n * HIST) * HD + t] = acc;
}

// ---------------- monolithic sequential queue march: ONE block ----------------
template <bool BF>
__global__ void __launch_bounds__(256)
k_run(const int* __restrict__ nbrs, const void* __restrict__ fmsg,
      const void* __restrict__ Wq, const void* __restrict__ bq,
      const void* __restrict__ bk, const void* __restrict__ br_,
      const void* __restrict__ Wm, const void* __restrict__ bm,
      const int* __restrict__ dS) {
  if ((g_dtype != 0) != BF) return;
  if (blockIdx.x != 0) return;
  const int t = threadIdx.x;
  const int wave = t >> 6, lane = t & 63;
  const int S = decode_S(dS);
  const int i64 = g_i64;

  __shared__ int   s_node[TOTAL];        // 20 KB
  __shared__ int   s_cnt[NN];
  __shared__ float s_msg[MD];
  __shared__ float s_feats[HIST][HD];    // 10 KB
  __shared__ float s_q[HD];
  __shared__ float s_vals[HD];
  __shared__ float s_ns[HD];
  __shared__ float s_red[4][HIST + 1];
  __shared__ float s_sc[HIST + 1];

  for (int i = t; i < TOTAL; i += 256) s_node[i] = (i < S) ? i : 0;
  for (int n = t; n < NN; n += 256) s_cnt[n] = 1;
  __syncthreads();

  volatile const float* vhist = g_hist;
  volatile const float* vmsg  = g_msgb;

  for (int i = 0; i < TOTAL; ++i) {
    const int n = s_node[i];
    const int c = s_cnt[n];
    const int v = (c < HIST) ? c : HIST;
    const int slot = c % HIST;
    const bool hc = (S + 8 * i) < TOTAL;

    if (i < S) s_msg[t] = ldin<BF>(fmsg, i * MD + t);
    else       s_msg[t] = finz(vmsg[((i - S) >> 3) * MD + t]);
#pragma unroll
    for (int j = 0; j < HIST; ++j)
      s_feats[j][t] = (j < v) ? finz(vhist[(n * HIST + j) * HD + t]) : 0.f;
    __syncthreads();

    // query = msg @ Wq + bq
    float q = ldin<BF>(bq, t);
    for (int m = 0; m < MD; ++m) q += s_msg[m] * ldin<BF>(Wq, m * HD + t);
    s_q[t] = q;
    __syncthreads();

    // kq[t] = Wk row t . query
    float kq = 0.f;
    for (int h = 0; h < HD; ++h) kq += s_q[h] * g_WkT[h * HD + t];

    // logits[j] = feats[j].kq (+ bk.q), block-reduced
    float part[HIST + 1];
#pragma unroll
    for (int j = 0; j < HIST; ++j) part[j] = s_feats[j][t] * kq;
    part[HIST] = ldin<BF>(bk, t) * q;
#pragma unroll
    for (int off = 32; off > 0; off >>= 1) {
#pragma unroll
      for (int j = 0; j <= HIST; ++j) part[j] += __shfl_down(part[j], off, 64);
    }
    if (lane == 0) {
#pragma unroll
      for (int j = 0; j <= HIST; ++j) s_red[wave][j] = part[j];
    }
    __syncthreads();
    if (t <= HIST) s_sc[t] = s_red[0][t] + s_red[1][t] + s_red[2][t] + s_red[3][t];
    __syncthreads();

    // softmax over valid slots
    const float bkq = s_sc[HIST];
    float lg[HIST];
#pragma unroll
    for (int j = 0; j < HIST; ++j)
      lg[j] = (j < v) ? ((s_sc[j] + bkq) * INV_SQRT_H) : -1e30f;
    float mx = lg[0];
#pragma unroll
    for (int j = 1; j < HIST; ++j) mx = fmaxf(mx, lg[j]);
    float e_[HIST], den = 0.f;
#pragma unroll
    for (int j = 0; j < HIST; ++j) { e_[j] = __expf(lg[j] - mx); den += e_[j]; }
    const float iden = 1.0f / den;
    float val = 0.f;
#pragma unroll
    for (int j = 0; j < HIST; ++j) val += e_[j] * s_feats[j][t];
    s_vals[t] = val * iden;
    __syncthreads();

    // newstate = values @ WrS + br -> hist[n][slot]
    float ns = ldin<BF>(br_, t);
    for (int h = 0; h < HD; ++h) ns += s_vals[h] * g_WrS[h * HD + t];
    g_hist[(size_t)(n * HIST + slot) * HD + t] = ns;
    s_ns[t] = ns;
    if (t == 0) s_cnt[n] = c + 1;
    if (hc && t < 8) s_node[S + 8 * i + t] = get_nbr(nbrs, i64, n, t);
    __syncthreads();

    // newmessage = [newstate, msg] @ Wm + bm
    if (hc) {
      float nm = ldin<BF>(bm, t);
      for (int h = 0; h < HD; ++h) nm += s_ns[h] * ldin<BF>(Wm, h * MD + t);
      for (int m = 0; m < MD; ++m) nm += s_msg[m] * ldin<BF>(Wm, (HD + m) * MD + t);
      g_msgb[(size_t)i * MD + t] = nm;
    }
    __syncthreads();
  }

  for (int n = t; n < NN; n += 256) g_counts[n] = s_cnt[n];
}

// ---------------- final projection + log_softmax ----------------
template <bool BF>
__global__ void k_out(const void* __restrict__ Wd, const void* __restrict__ bd,
                      void* __restrict__ out) {
  if ((g_dtype != 0) != BF) return;
  __shared__ float sf[HD];
  const int b = blockIdx.x;
  const int pp = b >> 9;
  const int n = b & 511;
  const int t = threadIdx.x;                 // 0..63 == O dim
  int cnt = g_counts[n];
  if (cnt < 1 || cnt > TOTAL + 1) cnt = 1;
  const int slot = (cnt - 1) % HIST;
  for (int h = t; h < HD; h += OD) sf[h] = finz(g_hist[(size_t)(n * HIST + slot) * HD + h]);
  __syncthreads();
  float acc = finz(ldin<BF>(bd, pp * OD + t));
  for (int h = 0; h < HD; ++h) acc += sf[h] * ldin<BF>(Wd, (pp * HD + h) * OD + t);
  acc = finz(acc);
  float mx = acc;
#pragma unroll
  for (int off = 32; off > 0; off >>= 1) mx = fmaxf(mx, __shfl_xor(mx, off, 64));
  float ex = __expf(acc - mx);
  float s = ex;
#pragma unroll
  for (int off = 32; off > 0; off >>= 1) s += __shfl_xor(s, off, 64);
  float r = finz(acc - mx - logf(s));
  const int oi = (pp * NN + n) * OD + t;
  if (BF) ((bf16*)out)[oi] = __float2bfloat16(r);
  else    ((float*)out)[oi] = r;
}

extern "C" void kernel_launch(void* const* d_in, const int* in_sizes, int n_in,
                              void* d_out, int out_size, void* d_ws, size_t ws_size,
                              hipStream_t stream) {
  const void* xa   = d_in[0];
  const int*  nbrs = (const int*)d_in[1];
  const void* fmsg = d_in[2];
  const void* We   = d_in[3];
  const void* be   = d_in[4];
  const void* Wq   = d_in[5];
  const void* bq   = d_in[6];
  const void* Wk   = d_in[7];
  const void* bk   = d_in[8];
  const void* Wr   = d_in[9];
  const void* br   = d_in[10];
  const void* Wm   = d_in[11];
  const void* bm   = d_in[12];
  const void* Wd   = d_in[13];
  const void* bd   = d_in[14];
  const int*  dS   = (const int*)d_in[15];
  (void)d_ws; (void)ws_size; (void)in_sizes; (void)n_in; (void)out_size;

  k_detect<<<dim3(1), dim3(64), 0, stream>>>((const unsigned*)xa, nbrs);

  k_prep<false><<<dim3(HD), dim3(256), 0, stream>>>(Wk, Wr);
  k_prep<true ><<<dim3(HD), dim3(256), 0, stream>>>(Wk, Wr);
  k_encode<false><<<dim3(NN), dim3(256), 0, stream>>>(xa, We, be);
  k_encode<true ><<<dim3(NN), dim3(256), 0, stream>>>(xa, We, be);
  k_run<false><<<dim3(1), dim3(256), 0, stream>>>(nbrs, fmsg, Wq, bq, bk, br, Wm, bm, dS);
  k_run<true ><<<dim3(1), dim3(256), 0, stream>>>(nbrs, fmsg, Wq, bq, bk, br, Wm, bm, dS);
  k_out<false><<<dim3(PD * NN), dim3(OD), 0, stream>>>(Wd, bd, d_out);
  k_out<true ><<<dim3(PD * NN), dim3(OD), 0, stream>>>(Wd, bd, d_out);
}

// Round 7
// 7448.656 us; speedup vs baseline: 9.2468x; 9.2468x over previous
//
#include <hip/hip_runtime.h>
#include <hip/hip_bf16.h>

#define NN 512
#define DEG 8
#define FD 128
#define HD 256
#define MD 256
#define OD 64
#define PD 2
#define HIST 10
#define TOTAL (10 * NN)       /* 5120 queue entries processed */
#define NPAR 648
#define INV_SQRT_H 0.0625f

typedef __hip_bfloat16 bf16;

// bit-level finite guard (fast-math-proof)
__device__ __forceinline__ float finz(float x) {
  unsigned u = __float_as_uint(x);
  return (((u >> 23) & 0xFFu) == 0xFFu) ? 0.f : x;
}

// dtype-polymorphic load: BF=true -> bf16 array, BF=false -> float array
template <bool BF>
__device__ __forceinline__ float ldin(const void* p, int idx) {
  if (BF) return __bfloat162float(((const bf16*)p)[idx]);
  return ((const float*)p)[idx];
}

// ---- static device scratch ----
__device__ float g_hist[NN * HIST * HD];    // ring buffers, 5.24 MB
__device__ float g_msgb[NPAR * MD];         // messages of entries with children
__device__ float g_WQK[HD * HD];            // Wq @ Wk^T   (kq = msg.WQK + ck)
__device__ float g_WrS[HD * HD];            // sum of 4 Wr row-blocks
__device__ float g_vq[HD];                  // Wq @ bk
__device__ float g_ck[HD];                  // Wk @ bq
__device__ float g_bqk;                     // bq . bk
__device__ int   g_node[TOTAL];
__device__ int   g_rank[TOTAL];
__device__ int   g_counts[NN];              // occurrences per node
__device__ int   g_nodedone[NN];
__device__ int   g_msgdone[NPAR];
__device__ int   g_dtype;                   // 1 = float tensors are bf16, 0 = float32
__device__ int   g_i64;                     // 1 = neighbors int64

__device__ __forceinline__ int decode_S(const int* dS) {
  int r = dS[0];
  if (r >= 1 && r <= NN) return r;
  float f = __int_as_float(r);
  if (f >= 1.f && f <= (float)NN) return (int)f;
  unsigned u = ((unsigned)r & 0xFFFFu) << 16;
  float g = __uint_as_float(u);
  if (g >= 1.f && g <= (float)NN) return (int)g;
  return 64;
}

__device__ __forceinline__ int get_nbr(const int* nbrs, int i64, int n, int d) {
  int v = i64 ? nbrs[2 * (n * DEG + d)] : nbrs[n * DEG + d];
  return (v < 0) ? 0 : (v >= NN ? NN - 1 : v);
}

// capped acquire-poll (system scope, cross-XCD safe); never hangs forever
__device__ __forceinline__ void poll_ge(int* p, int k) {
  for (int w = 0; w < (1 << 22); ++w) {
    if (__hip_atomic_load(p, __ATOMIC_ACQUIRE, __HIP_MEMORY_SCOPE_SYSTEM) >= k) return;
    __builtin_amdgcn_s_sleep(4);
  }
}

// ---------------- dtype detection from data statistics (validated round 6) ----------------
__global__ void k_detect(const unsigned* __restrict__ xa_words,
                         const int* __restrict__ nbrs_words) {
  if (threadIdx.x != 0 || blockIdx.x != 0) return;
  int cnt = 0;
  for (int w = 0; w < 64; ++w) {
    unsigned lo = xa_words[w] & 0xFFFFu;
    float vb = __uint_as_float(lo << 16);
    float av = fabsf(vb);
    if (av > 0.000244140625f && av < 64.f) ++cnt;
  }
  g_dtype = (cnt >= 32) ? 1 : 0;
  int allz = 1;
  for (int w = 1; w < 16; w += 2) allz &= (nbrs_words[w] == 0);
  g_i64 = allz;
}

// ---------------- zero the spin flags (no dtype gate) ----------------
__global__ void k_zero() {
  const int t = blockIdx.x * blockDim.x + threadIdx.x;
  if (t < NN) __hip_atomic_store(&g_nodedone[t], 0, __ATOMIC_RELAXED, __HIP_MEMORY_SCOPE_SYSTEM);
  if (t < NPAR) __hip_atomic_store(&g_msgdone[t], 0, __ATOMIC_RELAXED, __HIP_MEMORY_SCOPE_SYSTEM);
}

// ---------------- prep: weight folds (f32 accumulate) ----------------
template <bool BF>
__global__ void k_prep(const void* __restrict__ Wq, const void* __restrict__ Wk,
                       const void* __restrict__ Wr, const void* __restrict__ bq,
                       const void* __restrict__ bk) {
  if ((g_dtype != 0) != BF) return;
  const int b = blockIdx.x, t = threadIdx.x;
  const int wave = t >> 6, lane = t & 63;
  __shared__ float sw[HD];
  __shared__ float sr[4];
  if (b < HD) {
    sw[t] = ldin<BF>(Wq, b * HD + t);               // Wq row b
    __syncthreads();
    float acc = 0.f;                                // WQK[b][t] = sum_h Wq[b][h] Wk[t][h]
    for (int h = 0; h < HD; ++h) acc += sw[h] * ldin<BF>(Wk, t * HD + h);
    g_WQK[b * HD + t] = acc;
    float s = 0.f;                                  // WrS[b][t] = sum_q Wr[q*H+b][t]
#pragma unroll
    for (int q = 0; q < 4; ++q) s += ldin<BF>(Wr, (q * HD + b) * HD + t);
    g_WrS[b * HD + t] = s;
    float pv = sw[t] * ldin<BF>(bk, t);             // vq[b] = Wq row b . bk
#pragma unroll
    for (int off = 32; off > 0; off >>= 1) pv += __shfl_down(pv, off, 64);
    if (lane == 0) sr[wave] = pv;
    __syncthreads();
    if (t == 0) g_vq[b] = sr[0] + sr[1] + sr[2] + sr[3];
  } else {
    float a = 0.f;                                  // ck[t] = Wk row t . bq
    for (int h = 0; h < HD; ++h) a += ldin<BF>(Wk, t * HD + h) * ldin<BF>(bq, h);
    g_ck[t] = a;
    float pb = ldin<BF>(bq, t) * ldin<BF>(bk, t);   // bqk = bq . bk
#pragma unroll
    for (int off = 32; off > 0; off >>= 1) pb += __shfl_down(pb, off, 64);
    if (lane == 0) sr[wave] = pb;
    __syncthreads();
    if (t == 0) g_bqk = sr[0] + sr[1] + sr[2] + sr[3];
  }
}

// ---------------- encoded = xa @ We + be -> hist slot 0 ----------------
template <bool BF>
__global__ void k_encode(const void* __restrict__ xa, const void* __restrict__ We,
                         const void* __restrict__ be) {
  if ((g_dtype != 0) != BF) return;
  __shared__ float sxa[FD];
  int n = blockIdx.x, t = threadIdx.x;
  if (t < FD) sxa[t] = ldin<BF>(xa, n * FD + t);
  __syncthreads();
  float acc = ldin<BF>(be, t);
  for (int f = 0; f < FD; ++f) acc += sxa[f] * ldin<BF>(We, f * HD + t);
  g_hist[(size_t)(n * HIST) * HD + t] = acc;
}

// ---------------- schedule: queue node ids + per-node ranks + counts ----------------
__global__ void k_schedule(const int* __restrict__ nbrs, const int* __restrict__ dS) {
  __shared__ int s_node[TOTAL];                 // 20 KB
  __shared__ int s_rank[TOTAL];                 // 20 KB
  const int t = threadIdx.x;
  const int S = decode_S(dS);
  const int i64 = g_i64;
  for (int i = t; i < S; i += 1024) s_node[i] = i;
  __syncthreads();
  int done = S;
  while (done < TOTAL) {                        // BFS tree expansion, depth ~4
    long long nd = (long long)S + 8LL * (long long)done;
    int new_done = nd > (long long)TOTAL ? TOTAL : (int)nd;
    for (int i = done + t; i < new_done; i += 1024)
      s_node[i] = get_nbr(nbrs, i64, s_node[(i - S) >> 3], (i - S) & 7);
    __syncthreads();
    done = new_done;
  }
  if (t < NN) {                                 // per-node occurrence rank (LDS broadcast scan)
    int k = 0;
    for (int i = 0; i < TOTAL; ++i)
      if (s_node[i] == t) { s_rank[i] = k; ++k; }
    g_counts[t] = k;
  }
  __syncthreads();
  for (int i = t; i < TOTAL; i += 1024) { g_node[i] = s_node[i]; g_rank[i] = s_rank[i]; }
}

// ---------------- dependency-driven spin execution: block i == queue entry i ----------------
template <bool BF>
__global__ void __launch_bounds__(256)
k_steps(const int* __restrict__ nbrs, const void* __restrict__ fmsg,
        const void* __restrict__ br_, const void* __restrict__ Wm,
        const void* __restrict__ bm, const int* __restrict__ dS) {
  if ((g_dtype != 0) != BF) return;
  const int i = blockIdx.x;
  const int t = threadIdx.x;
  const int wave = t >> 6, lane = t & 63;
  const int S = decode_S(dS);
  const int n = g_node[i];
  const int k = g_rank[i];
  const int p = (i >= S) ? ((i - S) >> 3) : 0;
  const bool hc = (S + 8 * i) < TOTAL;
  const int c = k + 1;                           // reference count before this step
  const int v = (c < HIST) ? c : HIST;
  const int slot = c % HIST;

  __shared__ float s_msg[MD];
  __shared__ float s_feats[HIST][HD];
  __shared__ float s_vals[HD];
  __shared__ float s_ns[HD];
  __shared__ float s_red[4][HIST + 1];
  __shared__ float s_sc[HIST + 1];

  // ---- acquire: same-node predecessor + message parent ----
  if (t == 0) {
    poll_ge(&g_nodedone[n], k);
    if (i >= S) poll_ge(&g_msgdone[p], 1);
  }
  __syncthreads();
  __threadfence_system();                        // all threads: caches fresh for data reads

  if (i < S) s_msg[t] = ldin<BF>(fmsg, i * MD + t);
  else       s_msg[t] = finz(g_msgb[(size_t)p * MD + t]);
#pragma unroll
  for (int j = 0; j < HIST; ++j)
    s_feats[j][t] = (j < v) ? finz(g_hist[(size_t)(n * HIST + j) * HD + t]) : 0.f;
  __syncthreads();

  // kq[t] = Wk row t . query  ==  msg . WQK[:,t] + ck[t]
  float kq = g_ck[t];
  for (int m = 0; m < MD; ++m) kq += s_msg[m] * g_WQK[m * HD + t];

  // logits[j] = feats[j].kq ; bk.q = msg.vq + bqk   (block-reduced)
  float part[HIST + 1];
#pragma unroll
  for (int j = 0; j < HIST; ++j) part[j] = s_feats[j][t] * kq;
  part[HIST] = s_msg[t] * g_vq[t];
#pragma unroll
  for (int off = 32; off > 0; off >>= 1) {
#pragma unroll
    for (int j = 0; j <= HIST; ++j) part[j] += __shfl_down(part[j], off, 64);
  }
  if (lane == 0) {
#pragma unroll
    for (int j = 0; j <= HIST; ++j) s_red[wave][j] = part[j];
  }
  __syncthreads();
  if (t <= HIST) s_sc[t] = s_red[0][t] + s_red[1][t] + s_red[2][t] + s_red[3][t];
  __syncthreads();

  // softmax over valid slots
  const float bkq = s_sc[HIST] + g_bqk;
  float lg[HIST];
#pragma unroll
  for (int j = 0; j < HIST; ++j)
    lg[j] = (j < v) ? ((s_sc[j] + bkq) * INV_SQRT_H) : -1e30f;
  float mx = lg[0];
#pragma unroll
  for (int j = 1; j < HIST; ++j) mx = fmaxf(mx, lg[j]);
  float e_[HIST], den = 0.f;
#pragma unroll
  for (int j = 0; j < HIST; ++j) { e_[j] = __expf(lg[j] - mx); den += e_[j]; }
  const float iden = 1.0f / den;
  float val = 0.f;
#pragma unroll
  for (int j = 0; j < HIST; ++j) val += e_[j] * s_feats[j][t];
  s_vals[t] = val * iden;
  __syncthreads();

  // newstate = values @ WrS + br  -> hist[n][slot]
  float ns = ldin<BF>(br_, t);
  for (int h = 0; h < HD; ++h) ns += s_vals[h] * g_WrS[h * HD + t];
  g_hist[(size_t)(n * HIST + slot) * HD + t] = ns;
  if (hc) s_ns[t] = ns;
  __syncthreads();                               // vmcnt(0) drain: hist stores in L2
  // early release of the node chain (successor needs only hist)
  if (t == 0) {
    __threadfence_system();
    __hip_atomic_fetch_add(&g_nodedone[n], 1, __ATOMIC_RELEASE, __HIP_MEMORY_SCOPE_SYSTEM);
  }

  // newmessage = [newstate, msg] @ Wm + bm  (only entries with children)
  if (hc) {
    float nm = ldin<BF>(bm, t);
    for (int h = 0; h < HD; ++h) nm += s_ns[h] * ldin<BF>(Wm, h * MD + t);
    for (int m = 0; m < MD; ++m) nm += s_msg[m] * ldin<BF>(Wm, (HD + m) * MD + t);
    g_msgb[(size_t)i * MD + t] = nm;
    __syncthreads();                             // drain msg stores
    if (t == 0) {
      __threadfence_system();
      __hip_atomic_fetch_add(&g_msgdone[i], 1, __ATOMIC_RELEASE, __HIP_MEMORY_SCOPE_SYSTEM);
    }
  }
}

// ---------------- final projection + log_softmax ----------------
template <bool BF>
__global__ void k_out(const void* __restrict__ Wd, const void* __restrict__ bd,
                      void* __restrict__ out) {
  if ((g_dtype != 0) != BF) return;
  __shared__ float sf[HD];
  const int b = blockIdx.x;
  const int pp = b >> 9;
  const int n = b & 511;
  const int t = threadIdx.x;                     // 0..63 == O dim
  int occ = g_counts[n];
  if (occ < 0 || occ > TOTAL) occ = 0;
  const int slot = occ % HIST;                   // (count-1)%HIST with count = 1+occ
  for (int h = t; h < HD; h += OD) sf[h] = finz(g_hist[(size_t)(n * HIST + slot) * HD + h]);
  __syncthreads();
  float acc = finz(ldin<BF>(bd, pp * OD + t));
  for (int h = 0; h < HD; ++h) acc += sf[h] * ldin<BF>(Wd, (pp * HD + h) * OD + t);
  acc = finz(acc);
  float mx = acc;
#pragma unroll
  for (int off = 32; off > 0; off >>= 1) mx = fmaxf(mx, __shfl_xor(mx, off, 64));
  float ex = __expf(acc - mx);
  float s = ex;
#pragma unroll
  for (int off = 32; off > 0; off >>= 1) s += __shfl_xor(s, off, 64);
  float r = finz(acc - mx - logf(s));
  const int oi = (pp * NN + n) * OD + t;
  if (BF) ((bf16*)out)[oi] = __float2bfloat16(r);
  else    ((float*)out)[oi] = r;
}

extern "C" void kernel_launch(void* const* d_in, const int* in_sizes, int n_in,
                              void* d_out, int out_size, void* d_ws, size_t ws_size,
                              hipStream_t stream) {
  const void* xa   = d_in[0];
  const int*  nbrs = (const int*)d_in[1];
  const void* fmsg = d_in[2];
  const void* We   = d_in[3];
  const void* be   = d_in[4];
  const void* Wq   = d_in[5];
  const void* bq   = d_in[6];
  const void* Wk   = d_in[7];
  const void* bk   = d_in[8];
  const void* Wr   = d_in[9];
  const void* br   = d_in[10];
  const void* Wm   = d_in[11];
  const void* bm   = d_in[12];
  const void* Wd   = d_in[13];
  const void* bd   = d_in[14];
  const int*  dS   = (const int*)d_in[15];
  (void)d_ws; (void)ws_size; (void)in_sizes; (void)n_in; (void)out_size;

  k_detect<<<dim3(1), dim3(64), 0, stream>>>((const unsigned*)xa, nbrs);
  k_zero<<<dim3(3), dim3(256), 0, stream>>>();
  k_prep<false><<<dim3(HD + 1), dim3(256), 0, stream>>>(Wq, Wk, Wr, bq, bk);
  k_prep<true ><<<dim3(HD + 1), dim3(256), 0, stream>>>(Wq, Wk, Wr, bq, bk);
  k_encode<false><<<dim3(NN), dim3(256), 0, stream>>>(xa, We, be);
  k_encode<true ><<<dim3(NN), dim3(256), 0, stream>>>(xa, We, be);
  k_schedule<<<dim3(1), dim3(1024), 0, stream>>>(nbrs, dS);
  k_steps<false><<<dim3(TOTAL), dim3(256), 0, stream>>>(nbrs, fmsg, br, Wm, bm, dS);
  k_steps<true ><<<dim3(TOTAL), dim3(256), 0, stream>>>(nbrs, fmsg, br, Wm, bm, dS);
  k_out<false><<<dim3(PD * NN), dim3(OD), 0, stream>>>(Wd, bd, d_out);
  k_out<true ><<<dim3(PD * NN), dim3(OD), 0, stream>>>(Wd, bd, d_out);
}

// Round 8
// 1261.474 us; speedup vs baseline: 54.6000x; 5.9047x over previous
//
#include <hip/hip_runtime.h>
#include <hip/hip_bf16.h>

#define NN 512
#define DEG 8
#define FD 128
#define HD 256
#define MD 256
#define OD 64
#define PD 2
#define HIST 10
#define TOTAL (10 * NN)       /* 5120 queue entries processed */
#define NPAR 648              /* entries with children: i < (TOTAL-S)/8 <= 632 */
#define MAXL 40               /* parallel levels; level MAXL-1 = sequential tail */
#define SWEEPS 64             /* Jacobi sweeps; >= MAXL guarantees safe clamping */
#define INV_SQRT_H 0.0625f

typedef __hip_bfloat16 bf16;

// bit-level finite guard (fast-math-proof)
__device__ __forceinline__ float finz(float x) {
  unsigned u = __float_as_uint(x);
  return (((u >> 23) & 0xFFu) == 0xFFu) ? 0.f : x;
}

// runtime-dtype load: bf=1 -> bf16 array, bf=0 -> float array
__device__ __forceinline__ float ldin(const void* p, int idx, int bf) {
  if (bf) return __bfloat162float(((const bf16*)p)[idx]);
  return ((const float*)p)[idx];
}

// ---- static device scratch ----
__device__ float g_hist[NN * HIST * HD];    // ring buffers, 5.24 MB
__device__ float g_msgb[NPAR * MD];         // messages of entries with children
__device__ float g_WQK[HD * HD];            // Wq @ Wk^T   (kq = msg.WQK + ck)
__device__ float g_WrS[HD * HD];            // sum of 4 Wr row-blocks
__device__ float g_vq[HD];                  // Wq @ bk
__device__ float g_ck[HD];                  // Wk @ bq
__device__ float g_bqk;                     // bq . bk
__device__ int   g_node[TOTAL];
__device__ int   g_rank[TOTAL];
__device__ int   g_counts[NN];
__device__ int   g_list[TOTAL];             // entries bucketed by level (index-ascending)
__device__ int   g_meta[2 * MAXL];          // (start,count) per level
__device__ int   g_dtype;                   // 1 = float tensors are bf16
__device__ int   g_i64;                     // 1 = neighbors int64

__device__ __forceinline__ int decode_S(const int* dS) {
  int r = dS[0];
  if (r >= 1 && r <= NN) return r;
  float f = __int_as_float(r);
  if (f >= 1.f && f <= (float)NN) return (int)f;
  unsigned u = ((unsigned)r & 0xFFFFu) << 16;
  float g = __uint_as_float(u);
  if (g >= 1.f && g <= (float)NN) return (int)g;
  return 64;
}

__device__ __forceinline__ int get_nbr(const int* nbrs, int i64, int n, int d) {
  int v = i64 ? nbrs[2 * (n * DEG + d)] : nbrs[n * DEG + d];
  return (v < 0) ? 0 : (v >= NN ? NN - 1 : v);
}

// ---------------- schedule (incl. dtype detect): 1 block, 1024 threads ----------------
__global__ void __launch_bounds__(1024)
k_schedule(const unsigned* __restrict__ xa_w, const int* __restrict__ nbrs,
           const int* __restrict__ dS) {
  __shared__ int            s_node[TOTAL];   // 20 KB
  __shared__ int            s_np[TOTAL];     // 20 KB  prev same-node occurrence (-1 none)
  __shared__ unsigned short s_rank[TOTAL];   // 10 KB
  __shared__ short          s_lvl[TOTAL];    // 10 KB
  __shared__ int            s_lc[MAXL], s_ls[MAXL];
  __shared__ int            s_flags[2];      // [0]=i64, [1]=dtype
  const int t = threadIdx.x;

  if (t == 0) {                              // dtype + index-width detection (validated r6)
    int cnt = 0;
    for (int w = 0; w < 64; ++w) {
      unsigned lo = xa_w[w] & 0xFFFFu;
      float av = fabsf(__uint_as_float(lo << 16));
      if (av > 0.000244140625f && av < 64.f) ++cnt;
    }
    int bf = (cnt >= 32) ? 1 : 0;
    int allz = 1;
    for (int w = 1; w < 16; w += 2) allz &= (nbrs[w] == 0);
    g_dtype = bf; g_i64 = allz;
    s_flags[0] = allz; s_flags[1] = bf;
  }
  __syncthreads();
  const int i64 = s_flags[0];
  const int S = decode_S(dS);

  for (int i = t; i < TOTAL; i += 1024) { s_node[i] = (i < S) ? i : 0; s_lvl[i] = 0; }
  for (int l = t; l < MAXL; l += 1024) s_lc[l] = 0;
  __syncthreads();
  int done = S;                              // BFS queue expansion, depth ~4
  while (done < TOTAL) {
    long long nd = (long long)S + 8LL * (long long)done;
    int new_done = nd > (long long)TOTAL ? TOTAL : (int)nd;
    for (int i = done + t; i < new_done; i += 1024)
      s_node[i] = get_nbr(nbrs, i64, s_node[(i - S) >> 3], (i - S) & 7);
    __syncthreads();
    done = new_done;
  }
  if (t < NN) {                              // rank + prev-occurrence chains (broadcast scan)
    int last = -1, k = 0;
    for (int i = 0; i < TOTAL; ++i)
      if (s_node[i] == t) { s_rank[i] = (unsigned short)k; s_np[i] = last; last = i; ++k; }
    g_counts[t] = k;
  }
  __syncthreads();
  // Jacobi level relaxation: monotone from below; SWEEPS>=MAXL makes clamping safe
  for (int sw = 0; sw < SWEEPS; ++sw) {
    for (int i = t; i < TOTAL; i += 1024) {
      int a = -1;
      int np = s_np[i];
      if (np >= 0) a = s_lvl[np];
      if (i >= S) { int b = s_lvl[(i - S) >> 3]; if (b > a) a = b; }
      int nl = a + 1;
      if (nl > MAXL - 1) nl = MAXL - 1;
      if (nl > (int)s_lvl[i]) s_lvl[i] = (short)nl;
    }
    __syncthreads();
  }
  for (int i = t; i < TOTAL; i += 1024) atomicAdd(&s_lc[s_lvl[i]], 1);
  __syncthreads();
  if (t == 0) {
    int acc = 0;
    for (int l = 0; l < MAXL; ++l) { s_ls[l] = acc; acc += s_lc[l]; }
  }
  __syncthreads();
  if (t < MAXL) {                            // ordered scatter: ascending index per level
    int pos = s_ls[t];
    for (int i = 0; i < TOTAL; ++i)
      if ((int)s_lvl[i] == t) g_list[pos++] = i;
    g_meta[2 * t] = s_ls[t]; g_meta[2 * t + 1] = s_lc[t];
  }
  __syncthreads();
  for (int i = t; i < TOTAL; i += 1024) { g_node[i] = s_node[i]; g_rank[i] = s_rank[i]; }
}

// ---------------- weights fold + encode (one dispatch, 769 blocks) ----------------
__global__ void __launch_bounds__(256)
k_weights(const void* __restrict__ xa, const void* __restrict__ We,
          const void* __restrict__ be, const void* __restrict__ Wq,
          const void* __restrict__ Wk, const void* __restrict__ Wr,
          const void* __restrict__ bq, const void* __restrict__ bk) {
  const int b = blockIdx.x, t = threadIdx.x;
  const int bf = g_dtype;
  const int wave = t >> 6, lane = t & 63;
  __shared__ float sw[HD];
  __shared__ float sr[4];
  if (b < HD) {
    sw[t] = ldin(Wq, b * HD + t, bf);               // Wq row b
    __syncthreads();
    float acc = 0.f;                                // WQK[b][t] = Wq row b . Wk row t
    for (int h = 0; h < HD; ++h) acc += sw[h] * ldin(Wk, t * HD + h, bf);
    g_WQK[b * HD + t] = acc;
    float s = 0.f;
#pragma unroll
    for (int q = 0; q < 4; ++q) s += ldin(Wr, (q * HD + b) * HD + t, bf);
    g_WrS[b * HD + t] = s;
    float pv = sw[t] * ldin(bk, t, bf);             // vq[b] = Wq row b . bk
#pragma unroll
    for (int off = 32; off > 0; off >>= 1) pv += __shfl_down(pv, off, 64);
    if (lane == 0) sr[wave] = pv;
    __syncthreads();
    if (t == 0) g_vq[b] = sr[0] + sr[1] + sr[2] + sr[3];
  } else if (b == HD) {
    float a = 0.f;                                  // ck[t] = Wk row t . bq
    for (int h = 0; h < HD; ++h) a += ldin(Wk, t * HD + h, bf) * ldin(bq, h, bf);
    g_ck[t] = a;
    float pb = ldin(bq, t, bf) * ldin(bk, t, bf);
#pragma unroll
    for (int off = 32; off > 0; off >>= 1) pb += __shfl_down(pb, off, 64);
    if (lane == 0) sr[wave] = pb;
    __syncthreads();
    if (t == 0) g_bqk = sr[0] + sr[1] + sr[2] + sr[3];
  } else {                                          // encode node n
    const int n = b - HD - 1;
    if (t < FD) sw[t] = ldin(xa, n * FD + t, bf);
    __syncthreads();
    float acc = ldin(be, t, bf);
    for (int f = 0; f < FD; ++f) acc += sw[f] * ldin(We, f * HD + t, bf);
    g_hist[(size_t)(n * HIST) * HD + t] = acc;
  }
}

// ---------------- one attention step (256 threads cooperate) ----------------
__device__ __forceinline__ void step_body(
    int e, int S, int t, int bf,
    float* s_msg, float (*s_feats)[HD], float* s_vals, float* s_ns,
    float (*s_red)[HIST + 1], float* s_sc,
    const void* fmsg, const void* br_, const void* Wm, const void* bm) {
  const int n = g_node[e];
  const int k = g_rank[e];
  const int p = (e >= S) ? ((e - S) >> 3) : 0;
  const bool hc = (S + 8 * e) < TOTAL;
  const int c = k + 1;
  const int v = (c < HIST) ? c : HIST;
  const int slot = c % HIST;
  const int wave = t >> 6, lane = t & 63;

  s_msg[t] = (e < S) ? ldin(fmsg, e * MD + t, bf) : finz(g_msgb[(size_t)p * MD + t]);
#pragma unroll
  for (int j = 0; j < HIST; ++j)
    s_feats[j][t] = (j < v) ? finz(g_hist[(size_t)(n * HIST + j) * HD + t]) : 0.f;
  __syncthreads();

  // kq[t] = Wk row t . query  ==  msg . WQK[:,t] + ck[t]
  float kq = g_ck[t];
  for (int m = 0; m < MD; ++m) kq += s_msg[m] * g_WQK[m * HD + t];

  float part[HIST + 1];
#pragma unroll
  for (int j = 0; j < HIST; ++j) part[j] = s_feats[j][t] * kq;
  part[HIST] = s_msg[t] * g_vq[t];
#pragma unroll
  for (int off = 32; off > 0; off >>= 1) {
#pragma unroll
    for (int j = 0; j <= HIST; ++j) part[j] += __shfl_down(part[j], off, 64);
  }
  if (lane == 0) {
#pragma unroll
    for (int j = 0; j <= HIST; ++j) s_red[wave][j] = part[j];
  }
  __syncthreads();
  if (t <= HIST) s_sc[t] = s_red[0][t] + s_red[1][t] + s_red[2][t] + s_red[3][t];
  __syncthreads();

  const float bkq = s_sc[HIST] + g_bqk;
  float lg[HIST];
#pragma unroll
  for (int j = 0; j < HIST; ++j)
    lg[j] = (j < v) ? ((s_sc[j] + bkq) * INV_SQRT_H) : -1e30f;
  float mx = lg[0];
#pragma unroll
  for (int j = 1; j < HIST; ++j) mx = fmaxf(mx, lg[j]);
  float e_[HIST], den = 0.f;
#pragma unroll
  for (int j = 0; j < HIST; ++j) { e_[j] = __expf(lg[j] - mx); den += e_[j]; }
  const float iden = 1.0f / den;
  float val = 0.f;
#pragma unroll
  for (int j = 0; j < HIST; ++j) val += e_[j] * s_feats[j][t];
  s_vals[t] = val * iden;
  __syncthreads();

  float ns = ldin(br_, t, bf);
  for (int h = 0; h < HD; ++h) ns += s_vals[h] * g_WrS[h * HD + t];
  g_hist[(size_t)(n * HIST + slot) * HD + t] = ns;
  if (hc) s_ns[t] = ns;
  __syncthreads();

  if (hc) {
    float nm = ldin(bm, t, bf);
    if (bf) {
      const bf16* w = (const bf16*)Wm;
      for (int h = 0; h < HD; ++h) nm += s_ns[h] * __bfloat162float(w[h * MD + t]);
      for (int m = 0; m < MD; ++m) nm += s_msg[m] * __bfloat162float(w[(HD + m) * MD + t]);
    } else {
      const float* w = (const float*)Wm;
      for (int h = 0; h < HD; ++h) nm += s_ns[h] * w[h * MD + t];
      for (int m = 0; m < MD; ++m) nm += s_msg[m] * w[(HD + m) * MD + t];
    }
    g_msgb[(size_t)e * MD + t] = nm;
  }
  __syncthreads();   // LDS reuse guard
}

// ---------------- per-level executor ----------------
__global__ void __launch_bounds__(256)
k_level(const void* __restrict__ fmsg, const void* __restrict__ br_,
        const void* __restrict__ Wm, const void* __restrict__ bm,
        const int* __restrict__ dS, int lvl, int seq) {
  const int t = threadIdx.x;
  const int S = decode_S(dS);
  const int bf = g_dtype;
  const int start = g_meta[2 * lvl], count = g_meta[2 * lvl + 1];
  __shared__ float s_msg[MD];
  __shared__ float s_feats[HIST][HD];
  __shared__ float s_vals[HD];
  __shared__ float s_ns[HD];
  __shared__ float s_red[4][HIST + 1];
  __shared__ float s_sc[HIST + 1];
  if (seq) {
    if (blockIdx.x != 0) return;       // index-ascending => dependency-safe
    for (int idx = 0; idx < count; ++idx)
      step_body(g_list[start + idx], S, t, bf, s_msg, s_feats, s_vals, s_ns, s_red, s_sc,
                fmsg, br_, Wm, bm);
  } else {
    for (int idx = (int)blockIdx.x; idx < count; idx += (int)gridDim.x)
      step_body(g_list[start + idx], S, t, bf, s_msg, s_feats, s_vals, s_ns, s_red, s_sc,
                fmsg, br_, Wm, bm);
  }
}

// ---------------- final projection + log_softmax ----------------
__global__ void k_out(const void* __restrict__ Wd, const void* __restrict__ bd,
                      void* __restrict__ out) {
  __shared__ float sf[HD];
  const int b = blockIdx.x;
  const int pp = b >> 9;
  const int n = b & 511;
  const int t = threadIdx.x;                 // 0..63 == O dim
  const int bf = g_dtype;
  int occ = g_counts[n];
  if (occ < 0 || occ > TOTAL) occ = 0;
  const int slot = occ % HIST;               // (count-1)%HIST, count = 1+occ
  for (int h = t; h < HD; h += OD) sf[h] = finz(g_hist[(size_t)(n * HIST + slot) * HD + h]);
  __syncthreads();
  float acc = finz(ldin(bd, pp * OD + t, bf));
  for (int h = 0; h < HD; ++h) acc += sf[h] * ldin(Wd, (pp * HD + h) * OD + t, bf);
  acc = finz(acc);
  float mx = acc;
#pragma unroll
  for (int off = 32; off > 0; off >>= 1) mx = fmaxf(mx, __shfl_xor(mx, off, 64));
  float ex = __expf(acc - mx);
  float s = ex;
#pragma unroll
  for (int off = 32; off > 0; off >>= 1) s += __shfl_xor(s, off, 64);
  float r = finz(acc - mx - logf(s));
  const int oi = (pp * NN + n) * OD + t;
  if (bf) ((bf16*)out)[oi] = __float2bfloat16(r);
  else    ((float*)out)[oi] = r;
}

extern "C" void kernel_launch(void* const* d_in, const int* in_sizes, int n_in,
                              void* d_out, int out_size, void* d_ws, size_t ws_size,
                              hipStream_t stream) {
  const void* xa   = d_in[0];
  const int*  nbrs = (const int*)d_in[1];
  const void* fmsg = d_in[2];
  const void* We   = d_in[3];
  const void* be   = d_in[4];
  const void* Wq   = d_in[5];
  const void* bq   = d_in[6];
  const void* Wk   = d_in[7];
  const void* bk   = d_in[8];
  const void* Wr   = d_in[9];
  const void* br   = d_in[10];
  const void* Wm   = d_in[11];
  const void* bm   = d_in[12];
  const void* Wd   = d_in[13];
  const void* bd   = d_in[14];
  const int*  dS   = (const int*)d_in[15];
  (void)d_ws; (void)ws_size; (void)in_sizes; (void)n_in; (void)out_size;

  k_schedule<<<dim3(1), dim3(1024), 0, stream>>>((const unsigned*)xa, nbrs, dS);
  k_weights<<<dim3(HD + 1 + NN), dim3(256), 0, stream>>>(xa, We, be, Wq, Wk, Wr, bq, bk);
  for (int l = 0; l < MAXL - 1; ++l)
    k_level<<<dim3(512), dim3(256), 0, stream>>>(fmsg, br, Wm, bm, dS, l, 0);
  k_level<<<dim3(1), dim3(256), 0, stream>>>(fmsg, br, Wm, bm, dS, MAXL - 1, 1);
  k_out<<<dim3(PD * NN), dim3(OD), 0, stream>>>(Wd, bd, d_out);
}

// Round 9
// 666.443 us; speedup vs baseline: 103.3494x; 1.8928x over previous
//
#include <hip/hip_runtime.h>
#include <hip/hip_bf16.h>

#define NN 512
#define DEG 8
#define FD 128
#define HD 256
#define MD 256
#define OD 64
#define PD 2
#define HIST 10
#define TOTAL (10 * NN)       /* 5120 queue entries processed */
#define NPAR 648              /* entries with children: i < (TOTAL-S)/8 <= 632 */
#define MAXL 40               /* parallel levels; level MAXL-1 = sequential tail */
#define MAXSW 64              /* Jacobi sweep cap (early-exit typical ~10) */
#define INV_SQRT_H 0.0625f

typedef __hip_bfloat16 bf16;

// bit-level finite guard (fast-math-proof)
__device__ __forceinline__ float finz(float x) {
  unsigned u = __float_as_uint(x);
  return (((u >> 23) & 0xFFu) == 0xFFu) ? 0.f : x;
}

// runtime-dtype load: bf=1 -> bf16 array, bf=0 -> float array
__device__ __forceinline__ float ldin(const void* p, int idx, int bf) {
  if (bf) return __bfloat162float(((const bf16*)p)[idx]);
  return ((const float*)p)[idx];
}

// ---- static device scratch ----
__device__ float g_hist[NN * HIST * HD];    // ring buffers, 5.24 MB
__device__ float g_msgb[NPAR * MD];         // messages of entries with children
__device__ float g_WQK[HD * HD];            // Wq @ Wk^T   (kq = msg.WQK + ck)
__device__ float g_WrS[HD * HD];            // sum of 4 Wr row-blocks
__device__ float g_vq[HD];                  // Wq @ bk
__device__ float g_ck[HD];                  // Wk @ bq
__device__ float g_bqk;                     // bq . bk
__device__ int   g_node[TOTAL];
__device__ int   g_rank[TOTAL];
__device__ int   g_np[TOTAL];               // prev same-node occurrence (-1 none)
__device__ int   g_counts[NN];
__device__ int   g_list[TOTAL];             // entries bucketed by level
__device__ int   g_meta[2 * MAXL];          // (start,count) per level
__device__ int   g_dtype;                   // 1 = float tensors are bf16
__device__ int   g_i64;                     // 1 = neighbors int64

__device__ __forceinline__ int decode_S(const int* dS) {
  int r = dS[0];
  if (r >= 1 && r <= NN) return r;
  float f = __int_as_float(r);
  if (f >= 1.f && f <= (float)NN) return (int)f;
  unsigned u = ((unsigned)r & 0xFFFFu) << 16;
  float g = __uint_as_float(u);
  if (g >= 1.f && g <= (float)NN) return (int)g;
  return 64;
}

__device__ __forceinline__ int get_nbr(const int* nbrs, int i64, int n, int d) {
  int v = i64 ? nbrs[2 * (n * DEG + d)] : nbrs[n * DEG + d];
  return (v < 0) ? 0 : (v >= NN ? NN - 1 : v);
}

// ---------------- phase A: dtype detect + BFS queue expansion (1 block) ----------------
__global__ void __launch_bounds__(1024)
k_bfs(const unsigned* __restrict__ xa_w, const int* __restrict__ nbrs,
      const int* __restrict__ dS) {
  __shared__ int s_node[TOTAL];              // 20 KB
  __shared__ int s_flags[1];
  const int t = threadIdx.x;
  if (t == 0) {                              // dtype + index-width detection (validated r6)
    int cnt = 0;
    for (int w = 0; w < 64; ++w) {
      unsigned lo = xa_w[w] & 0xFFFFu;
      float av = fabsf(__uint_as_float(lo << 16));
      if (av > 0.000244140625f && av < 64.f) ++cnt;
    }
    g_dtype = (cnt >= 32) ? 1 : 0;
    int allz = 1;
    for (int w = 1; w < 16; w += 2) allz &= (nbrs[w] == 0);
    g_i64 = allz;
    s_flags[0] = allz;
  }
  __syncthreads();
  const int i64 = s_flags[0];
  const int S = decode_S(dS);
  for (int i = t; i < S; i += 1024) s_node[i] = i;
  __syncthreads();
  int done = S;
  while (done < TOTAL) {                     // message tree, depth ~4
    long long nd = (long long)S + 8LL * (long long)done;
    int new_done = nd > (long long)TOTAL ? TOTAL : (int)nd;
    for (int i = done + t; i < new_done; i += 1024)
      s_node[i] = get_nbr(nbrs, i64, s_node[(i - S) >> 3], (i - S) & 7);
    __syncthreads();
    done = new_done;
  }
  for (int i = t; i < TOTAL; i += 1024) g_node[i] = s_node[i];
}

// ---------------- phase B: rank + prev-occurrence, ballot-parallel (512 blocks x 64) ----
__global__ void __launch_bounds__(64)
k_rank() {
  const int n = blockIdx.x;                  // node id
  const int l = threadIdx.x;                 // lane
  int k = 0, last = -1;
  for (int base = 0; base < TOTAL; base += 64) {
    int nd = g_node[base + l];
    unsigned long long m = __ballot(nd == n);
    if (nd == n) {
      unsigned long long below = m & ((1ull << l) - 1ull);
      g_rank[base + l] = k + (int)__popcll(below);
      g_np[base + l] = below ? (base + 63 - (int)__builtin_clzll(below)) : last;
    }
    if (m) last = base + 63 - (int)__builtin_clzll(m);
    k += (int)__popcll(m);
  }
  if (l == 0) g_counts[n] = k;
}

// ---------------- phase C: levels (Jacobi + early exit) + bucket + scatter (1 block) ----
__global__ void __launch_bounds__(1024)
k_lvl(const int* __restrict__ dS) {
  __shared__ int   s_np[TOTAL];              // 20 KB
  __shared__ short s_lvl[TOTAL];             // 10 KB
  __shared__ int   s_lc[MAXL], s_ls[MAXL], s_cur[MAXL];
  __shared__ int   s_chg;
  const int t = threadIdx.x;
  const int S = decode_S(dS);
  for (int i = t; i < TOTAL; i += 1024) { s_np[i] = g_np[i]; s_lvl[i] = 0; }
  for (int l = t; l < MAXL; l += 1024) s_lc[l] = 0;
  __syncthreads();
  // chunk-ordered Jacobi (deps have smaller index -> near-Gauss-Seidel), early exit
  for (int sw = 0; sw < MAXSW; ++sw) {
    if (t == 0) s_chg = 0;
    __syncthreads();
    for (int ch = 0; ch < TOTAL; ch += 1024) {
      const int i = ch + t;
      int a = -1;
      int np = s_np[i];
      if (np >= 0) a = s_lvl[np];
      if (i >= S) { int b = s_lvl[(i - S) >> 3]; if (b > a) a = b; }
      int nl = a + 1;
      if (nl > MAXL - 1) nl = MAXL - 1;
      if (nl > (int)s_lvl[i]) { s_lvl[i] = (short)nl; s_chg = 1; }
      __syncthreads();                       // later chunks see this sweep's updates
    }
    if (!s_chg) break;
    __syncthreads();
  }
  __syncthreads();
  for (int i = t; i < TOTAL; i += 1024) atomicAdd(&s_lc[s_lvl[i]], 1);
  __syncthreads();
  if (t == 0) {
    int acc = 0;
    for (int l = 0; l < MAXL; ++l) { s_ls[l] = acc; s_cur[l] = acc; acc += s_lc[l]; }
  }
  __syncthreads();
  // parallel levels: unordered atomic scatter (entries within a level independent)
  for (int i = t; i < TOTAL; i += 1024) {
    int l = s_lvl[i];
    if (l < MAXL - 1) g_list[atomicAdd(&s_cur[l], 1)] = i;
  }
  if (t < MAXL) { g_meta[2 * t] = s_ls[t]; g_meta[2 * t + 1] = s_lc[t]; }
  __syncthreads();
  // tail level: MUST be index-ascending (sequential execution) — ballot-ordered scan
  if (t < 64) {
    int pos = s_ls[MAXL - 1];
    for (int base = 0; base < TOTAL; base += 64) {
      bool sel = (s_lvl[base + t] == MAXL - 1);
      unsigned long long m = __ballot(sel);
      if (sel) g_list[pos + (int)__popcll(m & ((1ull << t) - 1ull))] = base + t;
      pos += (int)__popcll(m);
    }
  }
}

// ---------------- weights fold + encode (one dispatch, HD+1+NN blocks) ----------------
__global__ void __launch_bounds__(256)
k_weights(const void* __restrict__ xa, const void* __restrict__ We,
          const void* __restrict__ be, const void* __restrict__ Wq,
          const void* __restrict__ Wk, const void* __restrict__ Wr,
          const void* __restrict__ bq, const void* __restrict__ bk) {
  const int b = blockIdx.x, t = threadIdx.x;
  const int bf = g_dtype;
  const int wave = t >> 6, lane = t & 63;
  __shared__ float sw[HD];
  __shared__ float sr[4];
  if (b < HD) {
    sw[t] = ldin(Wq, b * HD + t, bf);               // Wq row b
    __syncthreads();
    float a0 = 0.f, a1 = 0.f, a2 = 0.f, a3 = 0.f;   // WQK[b][t] = Wq row b . Wk row t
    for (int h = 0; h < HD; h += 4) {
      a0 += sw[h]     * ldin(Wk, t * HD + h,     bf);
      a1 += sw[h + 1] * ldin(Wk, t * HD + h + 1, bf);
      a2 += sw[h + 2] * ldin(Wk, t * HD + h + 2, bf);
      a3 += sw[h + 3] * ldin(Wk, t * HD + h + 3, bf);
    }
    g_WQK[b * HD + t] = (a0 + a1) + (a2 + a3);
    float s = 0.f;
#pragma unroll
    for (int q = 0; q < 4; ++q) s += ldin(Wr, (q * HD + b) * HD + t, bf);
    g_WrS[b * HD + t] = s;
    float pv = sw[t] * ldin(bk, t, bf);             // vq[b] = Wq row b . bk
#pragma unroll
    for (int off = 32; off > 0; off >>= 1) pv += __shfl_down(pv, off, 64);
    if (lane == 0) sr[wave] = pv;
    __syncthreads();
    if (t == 0) g_vq[b] = sr[0] + sr[1] + sr[2] + sr[3];
  } else if (b == HD) {
    float a = 0.f;                                  // ck[t] = Wk row t . bq
    for (int h = 0; h < HD; ++h) a += ldin(Wk, t * HD + h, bf) * ldin(bq, h, bf);
    g_ck[t] = a;
    float pb = ldin(bq, t, bf) * ldin(bk, t, bf);
#pragma unroll
    for (int off = 32; off > 0; off >>= 1) pb += __shfl_down(pb, off, 64);
    if (lane == 0) sr[wave] = pb;
    __syncthreads();
    if (t == 0) g_bqk = sr[0] + sr[1] + sr[2] + sr[3];
  } else {                                          // encode node n
    const int n = b - HD - 1;
    if (t < FD) sw[t] = ldin(xa, n * FD + t, bf);
    __syncthreads();
    float acc = ldin(be, t, bf);
    for (int f = 0; f < FD; ++f) acc += sw[f] * ldin(We, f * HD + t, bf);
    g_hist[(size_t)(n * HIST) * HD + t] = acc;
  }
}

// ---------------- one attention step (256 threads cooperate) ----------------
__device__ __forceinline__ void step_body(
    int e, int S, int t, int bf,
    float* s_msg, float (*s_feats)[HD], float* s_vals, float* s_ns,
    float (*s_red)[HIST + 1], float* s_sc,
    const void* fmsg, const void* br_, const void* Wm, const void* bm) {
  const int n = g_node[e];
  const int k = g_rank[e];
  const int p = (e >= S) ? ((e - S) >> 3) : 0;
  const bool hc = (S + 8 * e) < TOTAL;
  const int c = k + 1;
  const int v = (c < HIST) ? c : HIST;
  const int slot = c % HIST;
  const int wave = t >> 6, lane = t & 63;

  s_msg[t] = (e < S) ? ldin(fmsg, e * MD + t, bf) : finz(g_msgb[(size_t)p * MD + t]);
#pragma unroll
  for (int j = 0; j < HIST; ++j)
    s_feats[j][t] = (j < v) ? finz(g_hist[(size_t)(n * HIST + j) * HD + t]) : 0.f;
  __syncthreads();

  // kq[t] = Wk row t . query == msg . WQK[:,t] + ck[t]   (4-acc unroll: short dep chain)
  float a0 = 0.f, a1 = 0.f, a2 = 0.f, a3 = 0.f;
  for (int m = 0; m < MD; m += 4) {
    a0 += s_msg[m]     * g_WQK[(m)     * HD + t];
    a1 += s_msg[m + 1] * g_WQK[(m + 1) * HD + t];
    a2 += s_msg[m + 2] * g_WQK[(m + 2) * HD + t];
    a3 += s_msg[m + 3] * g_WQK[(m + 3) * HD + t];
  }
  const float kq = g_ck[t] + ((a0 + a1) + (a2 + a3));

  float part[HIST + 1];
#pragma unroll
  for (int j = 0; j < HIST; ++j) part[j] = s_feats[j][t] * kq;
  part[HIST] = s_msg[t] * g_vq[t];
#pragma unroll
  for (int off = 32; off > 0; off >>= 1) {
#pragma unroll
    for (int j = 0; j <= HIST; ++j) part[j] += __shfl_down(part[j], off, 64);
  }
  if (lane == 0) {
#pragma unroll
    for (int j = 0; j <= HIST; ++j) s_red[wave][j] = part[j];
  }
  __syncthreads();
  if (t <= HIST) s_sc[t] = s_red[0][t] + s_red[1][t] + s_red[2][t] + s_red[3][t];
  __syncthreads();

  const float bkq = s_sc[HIST] + g_bqk;
  float lg[HIST];
#pragma unroll
  for (int j = 0; j < HIST; ++j)
    lg[j] = (j < v) ? ((s_sc[j] + bkq) * INV_SQRT_H) : -1e30f;
  float mx = lg[0];
#pragma unroll
  for (int j = 1; j < HIST; ++j) mx = fmaxf(mx, lg[j]);
  float e_[HIST], den = 0.f;
#pragma unroll
  for (int j = 0; j < HIST; ++j) { e_[j] = __expf(lg[j] - mx); den += e_[j]; }
  const float iden = 1.0f / den;
  float val = 0.f;
#pragma unroll
  for (int j = 0; j < HIST; ++j) val += e_[j] * s_feats[j][t];
  s_vals[t] = val * iden;
  __syncthreads();

  float b0 = 0.f, b1 = 0.f, b2 = 0.f, b3 = 0.f;     // newstate = vals @ WrS + br
  for (int h = 0; h < HD; h += 4) {
    b0 += s_vals[h]     * g_WrS[(h)     * HD + t];
    b1 += s_vals[h + 1] * g_WrS[(h + 1) * HD + t];
    b2 += s_vals[h + 2] * g_WrS[(h + 2) * HD + t];
    b3 += s_vals[h + 3] * g_WrS[(h + 3) * HD + t];
  }
  const float ns = ldin(br_, t, bf) + ((b0 + b1) + (b2 + b3));
  g_hist[(size_t)(n * HIST + slot) * HD + t] = ns;
  if (hc) s_ns[t] = ns;
  __syncthreads();

  if (hc) {
    float c0 = 0.f, c1 = 0.f, c2 = 0.f, c3 = 0.f;
    if (bf) {
      const bf16* w = (const bf16*)Wm;
      for (int h = 0; h < HD; h += 4) {
        c0 += s_ns[h]     * __bfloat162float(w[(h)     * MD + t]);
        c1 += s_ns[h + 1] * __bfloat162float(w[(h + 1) * MD + t]);
        c2 += s_ns[h + 2] * __bfloat162float(w[(h + 2) * MD + t]);
        c3 += s_ns[h + 3] * __bfloat162float(w[(h + 3) * MD + t]);
      }
      for (int m = 0; m < MD; m += 4) {
        c0 += s_msg[m]     * __bfloat162float(w[(HD + m)     * MD + t]);
        c1 += s_msg[m + 1] * __bfloat162float(w[(HD + m + 1) * MD + t]);
        c2 += s_msg[m + 2] * __bfloat162float(w[(HD + m + 2) * MD + t]);
        c3 += s_msg[m + 3] * __bfloat162float(w[(HD + m + 3) * MD + t]);
      }
    } else {
      const float* w = (const float*)Wm;
      for (int h = 0; h < HD; h += 4) {
        c0 += s_ns[h]     * w[(h)     * MD + t];
        c1 += s_ns[h + 1] * w[(h + 1) * MD + t];
        c2 += s_ns[h + 2] * w[(h + 2) * MD + t];
        c3 += s_ns[h + 3] * w[(h + 3) * MD + t];
      }
      for (int m = 0; m < MD; m += 4) {
        c0 += s_msg[m]     * w[(HD + m)     * MD + t];
        c1 += s_msg[m + 1] * w[(HD + m + 1) * MD + t];
        c2 += s_msg[m + 2] * w[(HD + m + 2) * MD + t];
        c3 += s_msg[m + 3] * w[(HD + m + 3) * MD + t];
      }
    }
    g_msgb[(size_t)e * MD + t] = ldin(bm, t, bf) + ((c0 + c1) + (c2 + c3));
  }
  __syncthreads();   // LDS reuse guard
}

// ---------------- per-level executor ----------------
__global__ void __launch_bounds__(256)
k_level(const void* __restrict__ fmsg, const void* __restrict__ br_,
        const void* __restrict__ Wm, const void* __restrict__ bm,
        const int* __restrict__ dS, int lvl, int seq) {
  const int t = threadIdx.x;
  const int S = decode_S(dS);
  const int bf = g_dtype;
  const int start = g_meta[2 * lvl], count = g_meta[2 * lvl + 1];
  __shared__ float s_msg[MD];
  __shared__ float s_feats[HIST][HD];
  __shared__ float s_vals[HD];
  __shared__ float s_ns[HD];
  __shared__ float s_red[4][HIST + 1];
  __shared__ float s_sc[HIST + 1];
  if (seq) {
    if (blockIdx.x != 0) return;       // index-ascending => dependency-safe
    for (int idx = 0; idx < count; ++idx)
      step_body(g_list[start + idx], S, t, bf, s_msg, s_feats, s_vals, s_ns, s_red, s_sc,
                fmsg, br_, Wm, bm);
  } else {
    for (int idx = (int)blockIdx.x; idx < count; idx += (int)gridDim.x)
      step_body(g_list[start + idx], S, t, bf, s_msg, s_feats, s_vals, s_ns, s_red, s_sc,
                fmsg, br_, Wm, bm);
  }
}

// ---------------- final projection + log_softmax ----------------
__global__ void k_out(const void* __restrict__ Wd, const void* __restrict__ bd,
                      void* __restrict__ out) {
  __shared__ float sf[HD];
  const int b = blockIdx.x;
  const int pp = b >> 9;
  const int n = b & 511;
  const int t = threadIdx.x;                 // 0..63 == O dim
  const int bf = g_dtype;
  int occ = g_counts[n];
  if (occ < 0 || occ > TOTAL) occ = 0;
  const int slot = occ % HIST;               // (count-1)%HIST, count = 1+occ
  for (int h = t; h < HD; h += OD) sf[h] = finz(g_hist[(size_t)(n * HIST + slot) * HD + h]);
  __syncthreads();
  float acc = finz(ldin(bd, pp * OD + t, bf));
  for (int h = 0; h < HD; ++h) acc += sf[h] * ldin(Wd, (pp * HD + h) * OD + t, bf);
  acc = finz(acc);
  float mx = acc;
#pragma unroll
  for (int off = 32; off > 0; off >>= 1) mx = fmaxf(mx, __shfl_xor(mx, off, 64));
  float ex = __expf(acc - mx);
  float s = ex;
#pragma unroll
  for (int off = 32; off > 0; off >>= 1) s += __shfl_xor(s, off, 64);
  float r = finz(acc - mx - logf(s));
  const int oi = (pp * NN + n) * OD + t;
  if (bf) ((bf16*)out)[oi] = __float2bfloat16(r);
  else    ((float*)out)[oi] = r;
}

extern "C" void kernel_launch(void* const* d_in, const int* in_sizes, int n_in,
                              void* d_out, int out_size, void* d_ws, size_t ws_size,
                              hipStream_t stream) {
  const void* xa   = d_in[0];
  const int*  nbrs = (const int*)d_in[1];
  const void* fmsg = d_in[2];
  const void* We   = d_in[3];
  const void* be   = d_in[4];
  const void* Wq   = d_in[5];
  const void* bq   = d_in[6];
  const void* Wk   = d_in[7];
  const void* bk   = d_in[8];
  const void* Wr   = d_in[9];
  const void* br   = d_in[10];
  const void* Wm   = d_in[11];
  const void* bm   = d_in[12];
  const void* Wd   = d_in[13];
  const void* bd   = d_in[14];
  const int*  dS   = (const int*)d_in[15];
  (void)d_ws; (void)ws_size; (void)in_sizes; (void)n_in; (void)out_size;

  k_bfs<<<dim3(1), dim3(1024), 0, stream>>>((const unsigned*)xa, nbrs, dS);
  k_rank<<<dim3(NN), dim3(64), 0, stream>>>();
  k_lvl<<<dim3(1), dim3(1024), 0, stream>>>(dS);
  k_weights<<<dim3(HD + 1 + NN), dim3(256), 0, stream>>>(xa, We, be, Wq, Wk, Wr, bq, bk);
  for (int l = 0; l < MAXL - 1; ++l)
    k_level<<<dim3(512), dim3(256), 0, stream>>>(fmsg, br, Wm, bm, dS, l, 0);
  k_level<<<dim3(1), dim3(256), 0, stream>>>(fmsg, br, Wm, bm, dS, MAXL - 1, 1);
  k_out<<<dim3(PD * NN), dim3(OD), 0, stream>>>(Wd, bd, d_out);
}